// Round 9
// baseline (442.342 us; speedup 1.0000x reference)
//
#include <hip/hip_runtime.h>

// GAT layer: N=8192, IN_DIM=128, OUT_DIM=64, alpha=0.2
// out = elu( softmax_row( mask(lrelu(s1_i + s2_j), adj) ) @ Wh )
//
// R9: MEASUREMENT ROUND. R8 structure byte-for-byte except JC 8->4
// (grid 512 = 2 blocks/CU = 8 waves/CU) and launch_bounds (256,2) (no
// VGPR cap -> no spill confound). Purpose: if attn is latency-bound its
// dur ~doubles (>160us) and finally surfaces in rocprof top-5 WITH
// counters (FETCH_SIZE vs 268MB ideal, VALUBusy, LDS conflicts, MfmaUtil).
// If it stays invisible, the ~2TB/s ceiling is wave-count-independent ->
// throughput wall, different Round-10 attack.

#define N 8192
#define IN_DIM 128
#define OUT_DIM 64
#define ALPHA 0.2f
#define LOG2E 1.44269504088896f
#define JC 4        // j-chunks -> grid (128, 4) = 512 blocks = 2/CU
#define LDP 264     // LDS row stride in halfs (256 cols + 8 pad; 16B-aligned)

typedef _Float16 half8 __attribute__((ext_vector_type(8)));
typedef _Float16 h2 __attribute__((ext_vector_type(2)));
typedef float f32x4 __attribute__((ext_vector_type(4)));

static __device__ __forceinline__ h2 bc_h2(unsigned u) {
  return __builtin_bit_cast(h2, u);
}

// ---------------------------------------------------------------------------
// Kernel 1: Wh = x@W (fp16, transposed [f][i]); s1L/s2L = log2e * scores
// ---------------------------------------------------------------------------
__global__ __launch_bounds__(64) void wh_kernel(
    const float* __restrict__ x, const float* __restrict__ W,
    const float* __restrict__ a, _Float16* __restrict__ Wh_t,
    float* __restrict__ s1L, float* __restrict__ s2L) {
  __shared__ float xs[IN_DIM];
  const int i = blockIdx.x;
  const int t = threadIdx.x;

  xs[t]      = x[(size_t)i * IN_DIM + t];
  xs[t + 64] = x[(size_t)i * IN_DIM + 64 + t];
  __syncthreads();

  float wh = 0.f;
#pragma unroll
  for (int d = 0; d < IN_DIM; ++d) wh = fmaf(xs[d], W[d * OUT_DIM + t], wh);

  Wh_t[(size_t)t * N + i] = (_Float16)wh;

  float p1 = wh * a[t];
  float p2 = wh * a[64 + t];
#pragma unroll
  for (int off = 32; off; off >>= 1) {
    p1 += __shfl_down(p1, off);
    p2 += __shfl_down(p2, off);
  }
  if (t == 0) {
    s1L[i] = p1 * LOG2E;
    s2L[i] = p2 * LOG2E;
  }
}

// ---------------------------------------------------------------------------
// Kernel 2: mm = {m1, ML}: m1 = max(s1L), ML = lrelu(m1 + max(s2L)).
// ---------------------------------------------------------------------------
__global__ __launch_bounds__(256) void max_kernel(
    const float* __restrict__ s1L, const float* __restrict__ s2L,
    float* __restrict__ mm) {
  __shared__ float red[8];
  const int t = threadIdx.x;
  float m1 = -1e30f, m2 = -1e30f;
  for (int idx = t; idx < N; idx += 256) {
    m1 = fmaxf(m1, s1L[idx]);
    m2 = fmaxf(m2, s2L[idx]);
  }
#pragma unroll
  for (int off = 32; off; off >>= 1) {
    m1 = fmaxf(m1, __shfl_down(m1, off));
    m2 = fmaxf(m2, __shfl_down(m2, off));
  }
  if ((t & 63) == 0) {
    red[t >> 6] = m1;
    red[4 + (t >> 6)] = m2;
  }
  __syncthreads();
  if (t == 0) {
    m1 = fmaxf(fmaxf(red[0], red[1]), fmaxf(red[2], red[3]));
    m2 = fmaxf(fmaxf(red[4], red[5]), fmaxf(red[6], red[7]));
    float e = m1 + m2;
    mm[0] = m1;
    mm[1] = fmaxf(e, ALPHA * e);
  }
}

// ---------------------------------------------------------------------------
// Kernel 3: factor tables (split-shift keeps every factor <= 1, fp16-safe):
//   Fi[i] = half2{ 2^(s1-m1), 2^(.2(s1-m1)) }
//   TT[j/4] = 16B { T1[j..j+3], T2[j..j+3] }, T1 = 2^(s2-(ML-m1)),
//   T2 = 2^(.2*s2-(ML-.2*m1));  F1*T1 = 2^(s1+s2-ML), F2*T2 = 2^(.2(s1+s2)-ML)
// ---------------------------------------------------------------------------
__global__ __launch_bounds__(256) void ftab_kernel(
    const float* __restrict__ s1L, const float* __restrict__ s2L,
    const float* __restrict__ mm, unsigned int* __restrict__ Fi,
    _Float16* __restrict__ TTh) {
  const int j = blockIdx.x * 256 + threadIdx.x;
  const float m1 = mm[0], ML = mm[1];

  const float v1 = s1L[j] - m1;
  h2 f;
  f[0] = (_Float16)exp2f(v1);
  f[1] = (_Float16)exp2f(0.2f * v1);
  Fi[j] = __builtin_bit_cast(unsigned int, f);

  TTh[(j >> 2) * 8 + (j & 3)]     = (_Float16)exp2f(s2L[j] - (ML - m1));
  TTh[(j >> 2) * 8 + 4 + (j & 3)] =
      (_Float16)exp2f(0.2f * s2L[j] - (ML - 0.2f * m1));
}

// ---------------------------------------------------------------------------
// Kernel 4: pack B-fragments: Bpack[((kt*4+fg)*64+lane)*8] <- Wh_t frag.
// ---------------------------------------------------------------------------
__global__ __launch_bounds__(256) void bpack_kernel(
    const _Float16* __restrict__ Wh_t, _Float16* __restrict__ Bpack) {
  const int kt = blockIdx.x;
  const int t = threadIdx.x;
  const int fg = t >> 6;
  const int lane = t & 63;
  const int q = (t >> 4) & 3;
  const int r16 = t & 15;
  const half8 v =
      *(const half8*)(Wh_t + (size_t)(fg * 16 + r16) * N + kt * 32 + q * 8);
  *(half8*)(Bpack + ((size_t)(kt * 4 + fg) * 64 + lane) * 8) = v;
}

// ---------------------------------------------------------------------------
// Kernel 5: adj streamer. grid (N/64, JC); wave w: rows i0..i0+15,
// chunk cols [c*2048,+2048) in 8 k-tiles of 256. Every adj load is one row x
// 1 KB lane-contiguous. Per-wave LDS (no barriers).
// ---------------------------------------------------------------------------
__global__ __launch_bounds__(256, 2) void attn_kernel(
    const int* __restrict__ adj, const _Float16* __restrict__ Bpack,
    const unsigned int* __restrict__ Fi, const uint4* __restrict__ TT,
    float* __restrict__ accp, float* __restrict__ lp) {
  __shared__ __align__(16) _Float16 Ps[4 * 16 * LDP];  // 33792 B

  const int t = threadIdx.x;
  const int w = t >> 6;
  const int lane = t & 63;
  const int q = lane >> 4;
  const int r16 = lane & 15;
  const int i0 = blockIdx.x * 64 + w * 16;
  const int c = blockIdx.y;
  const int jb = c * (N / JC);  // 2048-col chunk

  _Float16* Pw = Ps + w * 16 * LDP;
  const _Float16* ldA = Pw + r16 * LDP + q * 8;

  half8 bones;
#pragma unroll
  for (int e = 0; e < 8; ++e)
    bones[e] = (r16 == 0) ? (_Float16)1.0f : (_Float16)0.0f;

  const unsigned fi_all = Fi[i0 + r16];  // rows 0..15 live in lanes 0..15
  const int* apb = adj + (size_t)i0 * N + jb + lane * 4;
  const uint4* ttb = TT + (jb >> 2) + lane;

  f32x4 acc[5] = {{0.f, 0.f, 0.f, 0.f}, {0.f, 0.f, 0.f, 0.f},
                  {0.f, 0.f, 0.f, 0.f}, {0.f, 0.f, 0.f, 0.f},
                  {0.f, 0.f, 0.f, 0.f}};

  for (int jt = 0; jt < (N / JC) / 256; ++jt) {  // 8 k-tiles of 256 cols
    const uint4 tt = ttb[jt * 64];  // this lane's 4 cols: T1 x4 | T2 x4

    // P build: 16 loads, each ONE row x 1 KB fully lane-contiguous
#pragma unroll
    for (int b = 0; b < 4; ++b) {
      int4 av[4];
#pragma unroll
      for (int rr = 0; rr < 4; ++rr)
        av[rr] = *(const int4*)(apb + (size_t)(b * 4 + rr) * N + jt * 256);
#pragma unroll
      for (int rr = 0; rr < 4; ++rr) {
        const int row = b * 4 + rr;
        const unsigned u = __shfl(fi_all, row);
        const h2 f1 = bc_h2((u & 0xFFFFu) * 0x00010001u);
        const h2 f2 = bc_h2((u >> 16) * 0x00010001u);
        const unsigned mlo = (unsigned)(av[rr].x | (av[rr].y << 16)) * 0x3C00u;
        const unsigned mhi = (unsigned)(av[rr].z | (av[rr].w << 16)) * 0x3C00u;
        const h2 plo =
            __builtin_elementwise_max(f1 * bc_h2(tt.x), f2 * bc_h2(tt.z)) *
            bc_h2(mlo);
        const h2 phi =
            __builtin_elementwise_max(f1 * bc_h2(tt.y), f2 * bc_h2(tt.w)) *
            bc_h2(mhi);
        uint2 pw;
        pw.x = __builtin_bit_cast(unsigned, plo);
        pw.y = __builtin_bit_cast(unsigned, phi);
        *(uint2*)(Pw + row * LDP + lane * 4) = pw;  // stride-1 row: conflict-free
      }
    }

    // MFMA: 8 k-steps of 32; A from per-wave LDS (same-wave order, no
    // barrier), B from L2-hot Bpack (+ ones column -> row sums)
    const int ktb = c * 64 + jt * 8;
#pragma unroll
    for (int ks = 0; ks < 8; ++ks) {
      const half8 aF = *(const half8*)(ldA + ks * 32);
      const _Float16* bp = Bpack + ((size_t)((ktb + ks) * 4) * 64 + lane) * 8;
#pragma unroll
      for (int fg = 0; fg < 4; ++fg) {
        const half8 bf = *(const half8*)(bp + (size_t)fg * 512);
        acc[fg] =
            __builtin_amdgcn_mfma_f32_16x16x32_f16(aF, bf, acc[fg], 0, 0, 0);
      }
      acc[4] =
          __builtin_amdgcn_mfma_f32_16x16x32_f16(aF, bones, acc[4], 0, 0, 0);
    }
  }

  // store partials. C/D: row = q*4+r, col = r16 (per fg block)
#pragma unroll
  for (int fg = 0; fg < 4; ++fg) {
#pragma unroll
    for (int r = 0; r < 4; ++r) {
      accp[((size_t)c * N + i0 + q * 4 + r) * OUT_DIM + fg * 16 + r16] =
          acc[fg][r];
    }
  }
  if (r16 == 0) {
#pragma unroll
    for (int r = 0; r < 4; ++r) lp[(size_t)c * N + i0 + q * 4 + r] = acc[4][r];
  }
}

// ---------------------------------------------------------------------------
// Kernel 6: combine JC partials, normalize, ELU.
// ---------------------------------------------------------------------------
__global__ __launch_bounds__(256) void reduce_kernel(
    const float* __restrict__ accp, const float* __restrict__ lp,
    float* __restrict__ out) {
  const int tid = blockIdx.x * 256 + threadIdx.x;
  const int i = tid >> 6;
  float s = 0.f, l = 0.f;
#pragma unroll
  for (int c = 0; c < JC; ++c) s += accp[(size_t)c * N * OUT_DIM + tid];
#pragma unroll
  for (int c = 0; c < JC; ++c) l += lp[(size_t)c * N + i];
  float v = s / l;
  out[tid] = v > 0.f ? v : expm1f(v);
}

// ---------------------------------------------------------------------------
extern "C" void kernel_launch(void* const* d_in, const int* in_sizes, int n_in,
                              void* d_out, int out_size, void* d_ws,
                              size_t ws_size, hipStream_t stream) {
  const float* x = (const float*)d_in[0];
  const int* adj = (const int*)d_in[1];
  const float* W = (const float*)d_in[2];
  const float* a = (const float*)d_in[3];
  float* out = (float*)d_out;

  char* ws = (char*)d_ws;
  _Float16* Wh_t = (_Float16*)ws;                       // 1 MiB
  float* s1L = (float*)(ws + (1u << 20));               // 32 KiB
  float* s2L = (float*)(ws + (1u << 20) + (64u << 10)); // 32 KiB
  float* mm = (float*)(ws + (1u << 20) + (128u << 10)); // 8 B
  unsigned* Fi = (unsigned*)(ws + (1u << 20) + (192u << 10));   // 32 KiB
  _Float16* TTh = (_Float16*)(ws + (1u << 20) + (256u << 10));  // 32 KiB
  _Float16* Bpack = (_Float16*)(ws + (2u << 20));       // 1 MiB
  float* accp = (float*)(ws + (4u << 20));              // JC*N*64*4 = 8 MiB
  float* lp = (float*)(ws + (20u << 20));               // 128 KiB

  wh_kernel<<<N, 64, 0, stream>>>(x, W, a, Wh_t, s1L, s2L);
  max_kernel<<<1, 256, 0, stream>>>(s1L, s2L, mm);
  ftab_kernel<<<N / 256, 256, 0, stream>>>(s1L, s2L, mm, Fi, TTh);
  bpack_kernel<<<N / 32, 256, 0, stream>>>(Wh_t, Bpack);
  attn_kernel<<<dim3(N / 64, JC), 256, 0, stream>>>(
      adj, Bpack, Fi, (const uint4*)TTh, accp, lp);
  reduce_kernel<<<N * OUT_DIM / 256, 256, 0, stream>>>(accp, lp, out);
}

// Round 10
// 422.265 us; speedup vs baseline: 1.0475x; 1.0475x over previous
//
#include <hip/hip_runtime.h>

// GAT layer: N=8192, IN_DIM=128, OUT_DIM=64, alpha=0.2
// out = elu( softmax_row( mask(lrelu(s1_i + s2_j), adj) ) @ Wh )
//
// R10: kill the B-fragment L2 stream (2.1 GB -> 64 MB), the wall that made
// R2-R9 invariant (~135us attn regardless of occupancy/contiguity/prefetch).
//  - Waves split OUTPUT FEATURES, not k: wave w holds B-frags for features
//    [w*16,+16) x all 16 k-steps of its block's 512-col chunk in REGISTERS
//    (64 VGPRs), loaded once per block.
//  - Block P tile (16 rows x 512 cols) in LDS, built cooperatively (each
//    wave converts the adj cols it streams); 2 barriers per row-group.
//  - Feature partials are disjoint -> accp stays 16 chunks (32 MB).
//  - LDP=520 halfs: LDP/8=65 odd -> b128 A-frag reads hit all 8 bank-groups
//    evenly (conflict-free).
//  - adj prefetch issued right after the P-visibility barrier -> in flight
//    through the MFMA phase; drained by the next barrier (which must wait
//    anyway).
// P math (R6-verified separable tables, no transcendentals in hot loop):
//   p_ij = max(F1_i*T1_j, F2_i*T2_j) * adj_ij, all factors <= 1 in fp16.

#define N 8192
#define IN_DIM 128
#define OUT_DIM 64
#define ALPHA 0.2f
#define LOG2E 1.44269504088896f
#define JC 16       // 512-col chunks
#define LDP 520     // LDS P row stride (halfs): 512 + 8; 520/8 odd
#define RG 8        // row-groups of 16 per block (128 rows/block)

typedef _Float16 half8 __attribute__((ext_vector_type(8)));
typedef _Float16 h2 __attribute__((ext_vector_type(2)));
typedef float f32x4 __attribute__((ext_vector_type(4)));

static __device__ __forceinline__ h2 bc_h2(unsigned u) {
  return __builtin_bit_cast(h2, u);
}

// ---------------------------------------------------------------------------
// Kernel 1: Wh = x@W (fp16, transposed [f][i]); s1L/s2L = log2e * scores
// ---------------------------------------------------------------------------
__global__ __launch_bounds__(64) void wh_kernel(
    const float* __restrict__ x, const float* __restrict__ W,
    const float* __restrict__ a, _Float16* __restrict__ Wh_t,
    float* __restrict__ s1L, float* __restrict__ s2L) {
  __shared__ float xs[IN_DIM];
  const int i = blockIdx.x;
  const int t = threadIdx.x;

  xs[t]      = x[(size_t)i * IN_DIM + t];
  xs[t + 64] = x[(size_t)i * IN_DIM + 64 + t];
  __syncthreads();

  float wh = 0.f;
#pragma unroll
  for (int d = 0; d < IN_DIM; ++d) wh = fmaf(xs[d], W[d * OUT_DIM + t], wh);

  Wh_t[(size_t)t * N + i] = (_Float16)wh;

  float p1 = wh * a[t];
  float p2 = wh * a[64 + t];
#pragma unroll
  for (int off = 32; off; off >>= 1) {
    p1 += __shfl_down(p1, off);
    p2 += __shfl_down(p2, off);
  }
  if (t == 0) {
    s1L[i] = p1 * LOG2E;
    s2L[i] = p2 * LOG2E;
  }
}

// ---------------------------------------------------------------------------
// Kernel 2: mm = {m1, ML}: m1 = max(s1L), ML = lrelu(m1 + max(s2L)).
// ---------------------------------------------------------------------------
__global__ __launch_bounds__(256) void max_kernel(
    const float* __restrict__ s1L, const float* __restrict__ s2L,
    float* __restrict__ mm) {
  __shared__ float red[8];
  const int t = threadIdx.x;
  float m1 = -1e30f, m2 = -1e30f;
  for (int idx = t; idx < N; idx += 256) {
    m1 = fmaxf(m1, s1L[idx]);
    m2 = fmaxf(m2, s2L[idx]);
  }
#pragma unroll
  for (int off = 32; off; off >>= 1) {
    m1 = fmaxf(m1, __shfl_down(m1, off));
    m2 = fmaxf(m2, __shfl_down(m2, off));
  }
  if ((t & 63) == 0) {
    red[t >> 6] = m1;
    red[4 + (t >> 6)] = m2;
  }
  __syncthreads();
  if (t == 0) {
    m1 = fmaxf(fmaxf(red[0], red[1]), fmaxf(red[2], red[3]));
    m2 = fmaxf(fmaxf(red[4], red[5]), fmaxf(red[6], red[7]));
    float e = m1 + m2;
    mm[0] = m1;
    mm[1] = fmaxf(e, ALPHA * e);
  }
}

// ---------------------------------------------------------------------------
// Kernel 3: factor tables (split-shift keeps every factor <= 1, fp16-safe):
//   Fi[i] = half2{ 2^(s1-m1), 2^(.2(s1-m1)) }
//   TT[j/4] = 16B { T1[j..j+3], T2[j..j+3] }, T1 = 2^(s2-(ML-m1)),
//   T2 = 2^(.2*s2-(ML-.2*m1)); F1*T1 = 2^(s1+s2-ML), F2*T2 = 2^(.2(s1+s2)-ML)
// ---------------------------------------------------------------------------
__global__ __launch_bounds__(256) void ftab_kernel(
    const float* __restrict__ s1L, const float* __restrict__ s2L,
    const float* __restrict__ mm, unsigned int* __restrict__ Fi,
    _Float16* __restrict__ TTh) {
  const int j = blockIdx.x * 256 + threadIdx.x;
  const float m1 = mm[0], ML = mm[1];

  const float v1 = s1L[j] - m1;
  h2 f;
  f[0] = (_Float16)exp2f(v1);
  f[1] = (_Float16)exp2f(0.2f * v1);
  Fi[j] = __builtin_bit_cast(unsigned int, f);

  TTh[(j >> 2) * 8 + (j & 3)]     = (_Float16)exp2f(s2L[j] - (ML - m1));
  TTh[(j >> 2) * 8 + 4 + (j & 3)] =
      (_Float16)exp2f(0.2f * s2L[j] - (ML - 0.2f * m1));
}

// ---------------------------------------------------------------------------
// Kernel 4: pack B-fragments: Bpack[((kt*4+fg)*64+lane)*8] <- Wh_t frag.
// ---------------------------------------------------------------------------
__global__ __launch_bounds__(256) void bpack_kernel(
    const _Float16* __restrict__ Wh_t, _Float16* __restrict__ Bpack) {
  const int kt = blockIdx.x;
  const int t = threadIdx.x;
  const int fg = t >> 6;
  const int lane = t & 63;
  const int q = (t >> 4) & 3;
  const int r16 = t & 15;
  const half8 v =
      *(const half8*)(Wh_t + (size_t)(fg * 16 + r16) * N + kt * 32 + q * 8);
  *(half8*)(Bpack + ((size_t)(kt * 4 + fg) * 64 + lane) * 8) = v;
}

// ---------------------------------------------------------------------------
// Kernel 5: adj streamer, feature-split. grid (N/128, JC).
// Block: 128 rows x 512 cols. Wave w: streams adj cols [jb+w*128,+128) into
// the shared P tile, MFMAs features [w*16,+16) over all 512 cols with B in
// registers. Wave 3 also accumulates the ones-column (row sums).
// ---------------------------------------------------------------------------
__global__ __launch_bounds__(256, 3) void attn_kernel(
    const int* __restrict__ adj, const _Float16* __restrict__ Bpack,
    const unsigned int* __restrict__ Fi, const uint4* __restrict__ TT,
    float* __restrict__ accp, float* __restrict__ lp) {
  __shared__ __align__(16) _Float16 Pb[16 * LDP];  // 16.25 KiB, block-shared

  const int t = threadIdx.x;
  const int w = t >> 6;
  const int lane = t & 63;
  const int q = lane >> 4;
  const int r16 = lane & 15;
  const int half_ = lane >> 5;  // row parity in the 2-row adj load
  const int l32 = lane & 31;    // col/4 within the wave's 128 cols
  const int ib0 = blockIdx.x * 128;
  const int c = blockIdx.y;
  const int jb = c * 512;
  const int jw = jb + w * 128;

  // B-frags: this wave's features (fg=w), all 16 k-steps. L2-hot, loaded once.
  half8 bw[16];
#pragma unroll
  for (int ks = 0; ks < 16; ++ks)
    bw[ks] = *(const half8*)(Bpack +
                             ((size_t)((c * 16 + ks) * 4 + w) * 64 + lane) * 8);

  half8 bones;
#pragma unroll
  for (int e = 0; e < 8; ++e)
    bones[e] = (r16 == 0) ? (_Float16)1.0f : (_Float16)0.0f;

  // column factors for this wave's 4 cols: constant across row-groups
  const uint4 tt = TT[(jw >> 2) + l32];
  const h2 t1lo = bc_h2(tt.x), t1hi = bc_h2(tt.y);
  const h2 t2lo = bc_h2(tt.z), t2hi = bc_h2(tt.w);

  // prefetch row-group 0: adj (8 x 1KB lane-contiguous, 2 rows each) + Fi
  const int* ap = adj + (size_t)(ib0 + half_) * N + jw + l32 * 4;
  int4 av[8];
#pragma unroll
  for (int it = 0; it < 8; ++it)
    av[it] = *(const int4*)(ap + (size_t)(2 * it) * N);
  unsigned fi = Fi[ib0 + r16];

  for (int rg = 0; rg < RG; ++rg) {
    const int i0 = ib0 + rg * 16;

    __syncthreads();  // P of previous rg fully consumed; av/fi arrived

    // ---- build this wave's 128-col slice of the 16x512 P tile
#pragma unroll
    for (int it = 0; it < 8; ++it) {
      const unsigned u = __shfl(fi, 2 * it + half_);
      const h2 f1 = bc_h2((u & 0xFFFFu) * 0x00010001u);
      const h2 f2 = bc_h2((u >> 16) * 0x00010001u);
      const unsigned mlo = (unsigned)(av[it].x | (av[it].y << 16)) * 0x3C00u;
      const unsigned mhi = (unsigned)(av[it].z | (av[it].w << 16)) * 0x3C00u;
      const h2 plo =
          __builtin_elementwise_max(f1 * t1lo, f2 * t2lo) * bc_h2(mlo);
      const h2 phi =
          __builtin_elementwise_max(f1 * t1hi, f2 * t2hi) * bc_h2(mhi);
      uint2 pw;
      pw.x = __builtin_bit_cast(unsigned, plo);
      pw.y = __builtin_bit_cast(unsigned, phi);
      *(uint2*)(Pb + (2 * it + half_) * LDP + w * 128 + l32 * 4) = pw;
    }

    __syncthreads();  // P visible to all waves

    // ---- prefetch next row-group (flies through the MFMA phase; the next
    //      barrier drains it, which it would have to anyway)
    const int rgn = (rg + 1) & (RG - 1);  // wrap: harmless reload on last
#pragma unroll
    for (int it = 0; it < 8; ++it)
      av[it] = *(const int4*)(ap + (size_t)(rgn * 16 + 2 * it) * N);
    fi = Fi[ib0 + rgn * 16 + r16];

    // ---- MFMA: 16 k-steps; A from shared P, B from registers
    f32x4 acc = {0.f, 0.f, 0.f, 0.f};
    f32x4 lacc = {0.f, 0.f, 0.f, 0.f};
#pragma unroll
    for (int ks = 0; ks < 16; ++ks) {
      const half8 aF = *(const half8*)(Pb + r16 * LDP + ks * 32 + q * 8);
      acc = __builtin_amdgcn_mfma_f32_16x16x32_f16(aF, bw[ks], acc, 0, 0, 0);
      if (w == 3)
        lacc =
            __builtin_amdgcn_mfma_f32_16x16x32_f16(aF, bones, lacc, 0, 0, 0);
    }

    // ---- store partials. C/D: row = q*4+r, col = r16; features w*16+r16
#pragma unroll
    for (int r = 0; r < 4; ++r) {
      accp[((size_t)c * N + i0 + q * 4 + r) * OUT_DIM + w * 16 + r16] =
          acc[r];
    }
    if (w == 3 && r16 == 0) {
#pragma unroll
      for (int r = 0; r < 4; ++r)
        lp[(size_t)c * N + i0 + q * 4 + r] = lacc[r];
    }
  }
}

// ---------------------------------------------------------------------------
// Kernel 6: combine JC partials, normalize, ELU.
// ---------------------------------------------------------------------------
__global__ __launch_bounds__(256) void reduce_kernel(
    const float* __restrict__ accp, const float* __restrict__ lp,
    float* __restrict__ out) {
  const int tid = blockIdx.x * 256 + threadIdx.x;
  const int i = tid >> 6;
  float s = 0.f, l = 0.f;
#pragma unroll
  for (int c = 0; c < JC; ++c) s += accp[(size_t)c * N * OUT_DIM + tid];
#pragma unroll
  for (int c = 0; c < JC; ++c) l += lp[(size_t)c * N + i];
  float v = s / l;
  out[tid] = v > 0.f ? v : expm1f(v);
}

// ---------------------------------------------------------------------------
extern "C" void kernel_launch(void* const* d_in, const int* in_sizes, int n_in,
                              void* d_out, int out_size, void* d_ws,
                              size_t ws_size, hipStream_t stream) {
  const float* x = (const float*)d_in[0];
  const int* adj = (const int*)d_in[1];
  const float* W = (const float*)d_in[2];
  const float* a = (const float*)d_in[3];
  float* out = (float*)d_out;

  char* ws = (char*)d_ws;
  _Float16* Wh_t = (_Float16*)ws;                       // 1 MiB
  float* s1L = (float*)(ws + (1u << 20));               // 32 KiB
  float* s2L = (float*)(ws + (1u << 20) + (64u << 10)); // 32 KiB
  float* mm = (float*)(ws + (1u << 20) + (128u << 10)); // 8 B
  unsigned* Fi = (unsigned*)(ws + (1u << 20) + (192u << 10));   // 32 KiB
  _Float16* TTh = (_Float16*)(ws + (1u << 20) + (256u << 10));  // 32 KiB
  _Float16* Bpack = (_Float16*)(ws + (2u << 20));       // 1 MiB
  float* accp = (float*)(ws + (4u << 20));              // JC*N*64*4 = 32 MiB
  float* lp = (float*)(ws + (40u << 20));               // 512 KiB

  wh_kernel<<<N, 64, 0, stream>>>(x, W, a, Wh_t, s1L, s2L);
  max_kernel<<<1, 256, 0, stream>>>(s1L, s2L, mm);
  ftab_kernel<<<N / 256, 256, 0, stream>>>(s1L, s2L, mm, Fi, TTh);
  bpack_kernel<<<N / 32, 256, 0, stream>>>(Wh_t, Bpack);
  attn_kernel<<<dim3(N / 128, JC), 256, 0, stream>>>(
      adj, Bpack, Fi, (const uint4*)TTh, accp, lp);
  reduce_kernel<<<N * OUT_DIM / 256, 256, 0, stream>>>(accp, lp, out);
}